// Round 2
// baseline (262.038 us; speedup 1.0000x reference)
//
#include <hip/hip_runtime.h>

// Problem constants (from reference setup_inputs)
#define Bq 2
#define Cq 2
#define Dq 128
#define Hq 224
#define Wq 224
#define HWq (Hq * Wq)          // 50176
#define DHWq (Dq * HWq)        // 6422528
#define CDHWq (Cq * DHWq)      // 12845056
#define NT 1024                // threads per block
#define SLAB (Dq * Wq)         // 28672 floats = one (b,c,h) slab = 112 KB
#define PER_T (SLAB / NT)      // 28 elements per thread
#define NV4 (SLAB / 4 / NT)    // 7 float4 staging insts per thread

typedef __attribute__((address_space(3))) void lds_void;
typedef const __attribute__((address_space(1))) void gbl_void;

// v3: DRAM-granularity restructure.
// v2 (90 us, 2.0 TB/s) touched memory in 128B runs (32-float w-tile) at
// 200KB stride -> HBM row-activate bound (~1KB pages, 128B/activate).
// v3: block = (b,h), stage the FULL src[b,c,:,h,:] slab (128z x 224w,
// 112 KB) one c at a time; every (c,z) row is now a full 896B contiguous
// run, and the block walks its slab flat-in-order (per j, the 16 waves
// cover a contiguous 4KB of (z,w) space). flow is register-cached across
// the c loop so demand traffic stays exactly minimal: 257 MB.
//  - 1 block/CU (112 KB LDS), 16 waves: fine if BW-bound as theorized.
//  - LDS banks: idx = z0*224 + w, 224 % 32 == 0 -> bank = w % 32,
//    64 consecutive-w lanes = 2 lanes/bank = free.
__global__ __launch_bounds__(NT, 4) void st_zwarp_v3_kernel(
    const float* __restrict__ src, const float* __restrict__ flow,
    float* __restrict__ out)
{
    __shared__ float s[SLAB];   // 112 KB: s[z*224 + w]

    const int tid = threadIdx.x;
    const int h = blockIdx.x % Hq;
    const int b = blockIdx.x / Hq;

    const float* src_bh  = src  + b * CDHWq + h * Wq;
    const float* flow_bh = flow + b * DHWq  + h * Wq;
    float*       out_bh  = out  + b * CDHWq + h * Wq;

    // ---- stage c=0 slab: src[b,0,:,h,:] -> LDS via direct DMA.
    // i is lane-consecutive (16B/lane) -> linear wave-uniform LDS dest.
#pragma unroll
    for (int j = 0; j < NV4; ++j) {
        const int i = (tid + j * NT) * 4;   // flat float idx in slab
        const int z = i / Wq;
        const int w = i - z * Wq;           // multiple of 4, row-aligned
        __builtin_amdgcn_global_load_lds(
            (gbl_void*)(src_bh + z * HWq + w),
            (lds_void*)(&s[i]), 16, 0, 0);
    }

    // ---- flow -> registers (completes during the barrier drain),
    // reused for both c values.
    float fl[PER_T];
#pragma unroll
    for (int j = 0; j < PER_T; ++j) {
        const int o = tid + j * NT;
        const int z = o / Wq;
        const int w = o - z * Wq;
        fl[j] = flow_bh[z * HWq + w];
    }

    __syncthreads();

    // ---- compute c=0: pure LDS + VALU + contiguous stores
#pragma unroll
    for (int j = 0; j < PER_T; ++j) {
        const int o = tid + j * NT;
        const int z = o / Wq;
        const int w = o - z * Wq;
        float zc = fminf(fmaxf((float)z + fl[j], 0.0f), (float)(Dq - 1));
        const float zf = floorf(zc);
        const int z0 = (int)zf;
        const float wz = zc - zf;
        const int z1 = min(z0 + 1, Dq - 1);
        const float s0 = s[z0 * Wq + w];
        const float s1 = s[z1 * Wq + w];
        out_bh[z * HWq + w] = s0 + (s1 - s0) * wz;
    }

    __syncthreads();   // all waves done reading s before overwrite

    // ---- stage c=1 slab: src[b,1,:,h,:]
#pragma unroll
    for (int j = 0; j < NV4; ++j) {
        const int i = (tid + j * NT) * 4;
        const int z = i / Wq;
        const int w = i - z * Wq;
        __builtin_amdgcn_global_load_lds(
            (gbl_void*)(src_bh + DHWq + z * HWq + w),
            (lds_void*)(&s[i]), 16, 0, 0);
    }

    __syncthreads();

    // ---- compute c=1
#pragma unroll
    for (int j = 0; j < PER_T; ++j) {
        const int o = tid + j * NT;
        const int z = o / Wq;
        const int w = o - z * Wq;
        float zc = fminf(fmaxf((float)z + fl[j], 0.0f), (float)(Dq - 1));
        const float zf = floorf(zc);
        const int z0 = (int)zf;
        const float wz = zc - zf;
        const int z1 = min(z0 + 1, Dq - 1);
        const float s0 = s[z0 * Wq + w];
        const float s1 = s[z1 * Wq + w];
        out_bh[DHWq + z * HWq + w] = s0 + (s1 - s0) * wz;
    }
}

extern "C" void kernel_launch(void* const* d_in, const int* in_sizes, int n_in,
                              void* d_out, int out_size, void* d_ws, size_t ws_size,
                              hipStream_t stream) {
    const float* src  = (const float*)d_in[0];
    const float* flow = (const float*)d_in[1];
    float* out = (float*)d_out;

    const int grid = Bq * Hq;   // 448 blocks = (b, h)
    st_zwarp_v3_kernel<<<grid, NT, 0, stream>>>(src, flow, out);
}

// Round 3
// 230.166 us; speedup vs baseline: 1.1385x; 1.1385x over previous
//
#include <hip/hip_runtime.h>

// Problem constants (from reference setup_inputs)
#define Bq 2
#define Cq 2
#define Dq 128
#define Hq 224
#define Wq 224
#define HWq (Hq * Wq)          // 50176
#define DHWq (Dq * HWq)        // 6422528
#define CDHWq (Cq * DHWq)      // 12845056
#define WT 112                 // w-tile (224 = 2*112; 112 floats = 448 B = 7 x 64B lines)
#define NWT (Wq / WT)          // 2
#define NT 512                 // threads per block
#define SLAB (Dq * WT)         // 14336 floats = 56 KB per (b,c,h,wt) slab
#define NV4 (SLAB / 4 / NT)    // 7 staging insts per thread
#define PER_T (SLAB / NT)      // 28 compute elements per thread

typedef __attribute__((address_space(3))) void lds_void;
typedef const __attribute__((address_space(1))) void gbl_void;

// v4: v3's DRAM-granularity lever + v2's exact-traffic discipline.
//  - v2 (90us): 128B runs -> 2.0 TB/s wall (HBM row-activate bound), traffic exact.
//  - v3 (122us): 896B runs -> 3.1 TB/s achieved, BUT 2.1x traffic blowup
//    (WRITE 100->231 MB, FETCH 75->141 MB); suspects: fl[28] live across two
//    loops at 64 VGPRs, 1024-thread blocks trashing L3 retention.
//  - v4: WT=112 (448B runs, 64B-aligned: 448 = 7*64), c split across blocks
//    so the compute loop keeps ONE flow value live (tiny VGPR). flow is read
//    by both c-blocks of a (b,h,wt) but the second read is an L3 hit -> HBM
//    demand stays exactly minimal (257 MB).
//  - 56 KB LDS, 512 thr -> 2 blocks/CU x 8 waves = 16 waves/CU.
//  - every 64B line of src/flow/out touched by exactly one wave instruction.
__global__ __launch_bounds__(NT, 4) void st_zwarp_v4_kernel(
    const float* __restrict__ src, const float* __restrict__ flow,
    float* __restrict__ out)
{
    __shared__ float s[SLAB];   // 56 KB: s[z*112 + w]

    const int tid = threadIdx.x;
    int blk = blockIdx.x;
    const int wt = blk & (NWT - 1);  blk >>= 1;   // NWT == 2
    const int c  = blk & 1;          blk >>= 1;   // Cq == 2
    const int h  = blk % Hq;
    const int b  = blk / Hq;

    const float* src_s  = src  + b * CDHWq + c * DHWq + h * Wq + wt * WT;
    const float* flow_s = flow + b * DHWq  + h * Wq + wt * WT;
    float*       out_s  = out  + b * CDHWq + c * DHWq + h * Wq + wt * WT;

    // ---- stage src[b,c,:,h,wt*112..+112) -> LDS via direct DMA.
    // i4 lane-consecutive (16B/lane) -> linear wave-uniform LDS dest; each
    // 16B load sits inside one 448B row (112 % 4 == 0), runs are 448B.
#pragma unroll
    for (int k = 0; k < NV4; ++k) {
        const int i4 = tid + k * NT;
        const int z = i4 / (WT / 4);            // i4 / 28
        const int w = (i4 - z * (WT / 4)) * 4;  // multiple of 4
        __builtin_amdgcn_global_load_lds(
            (gbl_void*)(src_s + z * HWq + w),
            (lds_void*)(&s[(z * WT + w)]), 16, 0, 0);
    }

    __syncthreads();

    // ---- compute: per j, one flow load + lerp + store. Only ~1 flow value
    // live at a time (compiler may pipeline a few) -> low VGPR, no spill.
    // Stores: 64 consecutive o per wave = 256B runs, 64B-aligned, full lines.
#pragma unroll
    for (int j = 0; j < PER_T; ++j) {
        const int o = tid + j * NT;
        const int z = o / WT;
        const int w = o - z * WT;
        const float fl = flow_s[z * HWq + w];
        float zc = fminf(fmaxf((float)z + fl, 0.0f), (float)(Dq - 1));
        const float zf = floorf(zc);
        const int z0 = (int)zf;
        const float wz = zc - zf;
        const int z1 = min(z0 + 1, Dq - 1);
        const float s0 = s[z0 * WT + w];
        const float s1 = s[z1 * WT + w];
        out_s[z * HWq + w] = s0 + (s1 - s0) * wz;
    }
}

extern "C" void kernel_launch(void* const* d_in, const int* in_sizes, int n_in,
                              void* d_out, int out_size, void* d_ws, size_t ws_size,
                              hipStream_t stream) {
    const float* src  = (const float*)d_in[0];
    const float* flow = (const float*)d_in[1];
    float* out = (float*)d_out;

    const int grid = Bq * Cq * Hq * NWT;   // 1792 blocks = (b, c, h, wt)
    st_zwarp_v4_kernel<<<grid, NT, 0, stream>>>(src, flow, out);
}

// Round 4
// 226.191 us; speedup vs baseline: 1.1585x; 1.0176x over previous
//
#include <hip/hip_runtime.h>

// Problem constants (from reference setup_inputs)
#define Bq 2
#define Cq 2
#define Dq 128
#define Hq 224
#define Wq 224
#define HWq (Hq * Wq)          // 50176
#define DHWq (Dq * HWq)        // 6422528
#define CDHWq (Cq * DHWq)      // 12845056
#define WT 112                 // w-tile (224 = 2*112; 112 floats = 448 B = 7 x 64B lines)
#define NWT (Wq / WT)          // 2
#define NT 512                 // threads per block
#define SLAB (Dq * WT)         // 14336 floats = 56 KB per (b,c,h,wt) slab
#define NV4 (SLAB / 4 / NT)    // 7 staging insts per thread
#define PER_T (SLAB / NT)      // 28 compute elements per thread

typedef __attribute__((address_space(3))) void lds_void;
typedef const __attribute__((address_space(1))) void gbl_void;

// v5 = v4 + NON-TEMPORAL output stores. Single-lever change.
//
// Evidence trail:
//  - v1/v2/v4 all pinned at ~88us despite BW 2.0->2.5 TB/s: the achieved BW
//    scales with run length (128B->2.0, 448B->2.5, 896B->3.1 TB/s) but
//    traffic moved inversely. Remaining lever is BYTES, not BW.
//  - Working set src(103)+flow(51)+out(103) = 257 MB == L3 capacity. The
//    output allocating in L3 evicts the inputs each dispatch -> FETCH
//    stays 75-115 MB instead of ~0. Inputs alone (154 MB) fit easily.
//  - Fix: out stores use the nt flag (no-allocate) so src+flow stay
//    L3-resident across dispatches; steady-state HBM traffic ~= writes only.
//
// Structure (unchanged from v4): block = (b,c,h,wt), WT=112 -> all streams
// move in 448B 64B-aligned runs; src staged once via global_load_lds;
// each 64B line touched by exactly one wave instruction.
__global__ __launch_bounds__(NT, 4) void st_zwarp_v5_kernel(
    const float* __restrict__ src, const float* __restrict__ flow,
    float* __restrict__ out)
{
    __shared__ float s[SLAB];   // 56 KB: s[z*112 + w]

    const int tid = threadIdx.x;
    int blk = blockIdx.x;
    const int wt = blk & (NWT - 1);  blk >>= 1;   // NWT == 2
    const int c  = blk & 1;          blk >>= 1;   // Cq == 2
    const int h  = blk % Hq;
    const int b  = blk / Hq;

    const float* src_s  = src  + b * CDHWq + c * DHWq + h * Wq + wt * WT;
    const float* flow_s = flow + b * DHWq  + h * Wq + wt * WT;
    float*       out_s  = out  + b * CDHWq + c * DHWq + h * Wq + wt * WT;

    // ---- stage src[b,c,:,h,wt*112..+112) -> LDS via direct DMA.
    // i4 lane-consecutive (16B/lane) -> linear wave-uniform LDS dest.
#pragma unroll
    for (int k = 0; k < NV4; ++k) {
        const int i4 = tid + k * NT;
        const int z = i4 / (WT / 4);            // i4 / 28
        const int w = (i4 - z * (WT / 4)) * 4;  // multiple of 4
        __builtin_amdgcn_global_load_lds(
            (gbl_void*)(src_s + z * HWq + w),
            (lds_void*)(&s[(z * WT + w)]), 16, 0, 0);
    }

    __syncthreads();

    // ---- compute: per j, one flow load + lerp + nt-store.
    // Stores: 64 consecutive o per wave = 256B runs, full lines, nt flag
    // -> no L3 allocation -> inputs stay LLC-resident across dispatches.
#pragma unroll
    for (int j = 0; j < PER_T; ++j) {
        const int o = tid + j * NT;
        const int z = o / WT;
        const int w = o - z * WT;
        const float fl = flow_s[z * HWq + w];
        float zc = fminf(fmaxf((float)z + fl, 0.0f), (float)(Dq - 1));
        const float zf = floorf(zc);
        const int z0 = (int)zf;
        const float wz = zc - zf;
        const int z1 = min(z0 + 1, Dq - 1);
        const float s0 = s[z0 * WT + w];
        const float s1 = s[z1 * WT + w];
        __builtin_nontemporal_store(s0 + (s1 - s0) * wz,
                                    &out_s[z * HWq + w]);
    }
}

extern "C" void kernel_launch(void* const* d_in, const int* in_sizes, int n_in,
                              void* d_out, int out_size, void* d_ws, size_t ws_size,
                              hipStream_t stream) {
    const float* src  = (const float*)d_in[0];
    const float* flow = (const float*)d_in[1];
    float* out = (float*)d_out;

    const int grid = Bq * Cq * Hq * NWT;   // 1792 blocks = (b, c, h, wt)
    st_zwarp_v5_kernel<<<grid, NT, 0, stream>>>(src, flow, out);
}